// Round 3
// baseline (217.976 us; speedup 1.0000x reference)
//
#include <hip/hip_runtime.h>

// EquiConv fused MFMA kernel for MI355X (gfx950) — round 8.
// R7 + deep per-wave DMA pipeline. Diagnosis: K-steps cost ~3.4Kcy each while
// only ~1.4Kcy is issue (VALUBusy 28 + MfmaUtil 16) -> all waves vmcnt-stalled;
// L2 BW at 26% of ceiling; regs (124 VGPR + 96 acc) cap 2 waves/SIMD so TLP
// can't grow. Fix: per-wave depth. Ring re-geometry: 3KB half-chunks, 11 slots
// per wave (33KB), depth-10 prefetch (30KB in flight vs 12KB), ONE counted
// vmcnt wait per half-step (27 steady; explicit 27->0 drain ladder in the
// fully-unrolled VS tail). WAITL0 eliminated: the slot DMA(h+10) overwrites
// was read at step h-1 and retired via the lgkm waits its MFMAs required.
// LDS: single 145,664B pool (ring 132K + x1 10.5K; hb & redf alias dead
// regions) -> 1 block/CU, launch_bounds(256,1). Peak outstanding vmem =
// 32 hoist + 30 DMA = 62 <= 63 (no queue-full stall). Accumulation order
// unchanged -> expect bit-identical output (absmax 0.09375) as a canary.
// prep_weights unchanged from R7 (dest-linear gather).

#define E_TOT 20000

typedef __attribute__((ext_vector_type(8))) short short8;
typedef __attribute__((ext_vector_type(4))) float f32x4;
typedef __attribute__((ext_vector_type(2))) __bf16 bf16x2;

#define FRAG_USH 512
#define HALF_USH 1536          // 3 frags = 3KB
#define CH_USH   3072          // 6 frags = 6KB (stream layout unit)
#define N_CH     52
#define NH       104           // 2*N_CH half-chunks
#define NSLOT    11            // ring slots per wave
#define STRIDE_W 159744        // 312 frags * 512 ushort per wave stream
#define FC1_OFF  638976        // 4*STRIDE_W
#define FC2_OFF  647168
#define FC3_OFF  651264
#define WS_USH   657408        // 1.28 MB of d_ws

// LDS pool carve (bytes)
#define RING_B   135168        // 4 waves * 11 slots * 3072B
#define X1S_OFF  135168
#define X1V_OFF  139392        // +32*66*2
#define POOL_B   145664        // +32*98*2

__device__ __forceinline__ unsigned short f2b(float f){
  return __builtin_bit_cast(unsigned short, (__bf16)f);
}
__device__ __forceinline__ unsigned f2b2(float lo, float hi){
  bf16x2 t; t[0] = (__bf16)lo; t[1] = (__bf16)hi;
  return __builtin_bit_cast(unsigned, t);
}
__device__ __forceinline__ float b2f(unsigned short h){
  return __uint_as_float(((unsigned)h) << 16);
}
__device__ __forceinline__ f32x4 mfma16(short8 a, short8 b, f32x4 c){
  return __builtin_amdgcn_mfma_f32_16x16x32_bf16(a, b, c, 0, 0, 0);
}
union U8 { short8 v; unsigned u[4]; };
__device__ __forceinline__ float silu_f(float x){ return x/(1.f+__expf(-x)); }
__device__ __forceinline__ float sigm_f(float x){ return 1.f/(1.f+__expf(-x)); }

#define PACK8(a, s, x) \
  a.u[0]=f2b2((s)*(x)[0],(s)*(x)[1]); a.u[1]=f2b2((s)*(x)[2],(s)*(x)[3]); \
  a.u[2]=f2b2((s)*(x)[4],(s)*(x)[5]); a.u[3]=f2b2((s)*(x)[6],(s)*(x)[7]);

// s_waitcnt simm16: vmcnt[3:0]|[15:14], expcnt[6:4], lgkmcnt[11:8]
// vmcnt codes: 27=0x4F7B 24=0x4F78 21=0x4F75 18=0x4F72 15=0x0F7F 12=0x0F7C
//              9=0x0F79 6=0x0F76 3=0x0F73 0=0x0F70
#define WV(code) { __builtin_amdgcn_s_waitcnt(code); __builtin_amdgcn_sched_barrier(0); }

// dest position of (k_local, n16) inside a 512-ushort fragment
__device__ __forceinline__ int fpos(int kl, int n16){
  return (kl>>3)*128 + n16*8 + (kl&7);
}

// ---------------- prep: dest-linear gather into per-wave streams ----------------
__global__ void prep_weights(const float* __restrict__ ss_s, const float* __restrict__ ss_g,
                             const float* __restrict__ vv_s, const float* __restrict__ vv_g,
                             const float* __restrict__ sv,   const float* __restrict__ vs,
                             const float* __restrict__ w1,   const float* __restrict__ w2,
                             const float* __restrict__ w3,   unsigned short* __restrict__ wsb)
{
  int g = blockIdx.x * 256 + threadIdx.x;
  if (g >= WS_USH/8) return;
  const int dest = g << 3;
  const float A_SC  = 0.013975424859373686f;                     // 1/sqrt(S*S+V*V)
  const float A_VV  = (float)(0.013975424859373686 * 0.5773502691896258);
  const float A_VEC = 0.015625f;                                 // 1/sqrt(2*S*V)

  const float* src = nullptr;
  int stride = 0;
  float scale = 1.f;

  if (dest < FC1_OFF) {                      // 4 per-wave streams
    int wave = dest / STRIDE_W;
    int off  = dest - wave*STRIDE_W;
    int c    = off / CH_USH;
    int rem  = off - c*CH_USH;
    int t    = rem >> 9;                     // fragment 0..5
    int p    = rem & 511;
    int kl   = (p >> 7) << 3;                // base kl; +j inside group
    int n16  = (p >> 3) & 15;
    if (c < 32) {                            // SS: ss_s (t0..3) + ss_g (t4,5)
      int u = (wave<<4) + (c>>1);
      int v = ((c&1)<<5) + kl;
      if (t < 4) { src = ss_s + (u<<12)+(v<<6)+((t<<4)+n16);     stride = 64; }
      else       { src = ss_g + (u<<11)+(v<<5)+(((t-4)<<4)+n16); stride = 32; }
      scale = A_SC;
    } else if (c < 40) {                     // VV: vv_s (t0..3) + vv_g (t4,5)
      int u = (wave<<3) + (c-32);
      int v = kl;
      if (t < 4) { src = vv_s + (u<<11)+(v<<6)+((t<<4)+n16);     stride = 64; }
      else       { src = vv_g + (u<<10)+(v<<5)+(((t-4)<<4)+n16); stride = 32; }
      scale = A_VV;
    } else if (c < 46) {                     // SV: chunks 40..45, ul = ch*3 + t/2
      int ul = (c-40)*3 + (t>>1);
      if (ul < 16) {
        int u = (wave<<4) + ul;
        src = sv + (u<<10)+(kl<<5)+(((t&1)<<4)+n16);
        stride = 32; scale = A_VEC;
      }                                      // else: gap frag (c=45,t>=2) -> 0
    } else {                                 // VS: chunks 46..51
      int cc = c - 46;
      int vh = cc/3, ch3 = cc - vh*3;
      int fseq = ch3*6 + t;
      if (fseq < 16) {
        int u = (wave<<3) + (fseq>>1);
        int v = (vh<<5) + kl;
        src = vs + (u<<11)+(v<<5)+(((fseq&1)<<4)+n16);
        stride = 32; scale = A_VEC;
      }                                      // else: gap frag (ch3=2,t>=4) -> 0
    }
  } else if (dest < FC2_OFF) {               // fc1 [128][64]
    int off = dest - FC1_OFF;
    int fi = off >> 9, p = off & 511;
    int kl = (p>>7)<<3, n16 = (p>>3)&15;
    int k = ((fi>>2)<<5) + kl, n = ((fi&3)<<4) + n16;
    src = w1 + (k<<6) + n; stride = 64;
  } else if (dest < FC3_OFF) {               // fc2 [64][64]
    int off = dest - FC2_OFF;
    int fi = off >> 9, p = off & 511;
    int kl = (p>>7)<<3, n16 = (p>>3)&15;
    int k = ((fi>>2)<<5) + kl, n = ((fi&3)<<4) + n16;
    src = w2 + (k<<6) + n; stride = 64;
  } else {                                   // fc3 [64][96]
    int off = dest - FC3_OFF;
    int fi = off >> 9, p = off & 511;
    int kl = (p>>7)<<3, n16 = (p>>3)&15;
    int koff = fi/6, nhi = fi - koff*6;
    int k = (koff<<5) + kl, n = (nhi<<4) + n16;
    src = w3 + k*96 + n; stride = 96;
  }

  U8 a;
  if (src) {
    float v0 = scale * src[0*stride], v1 = scale * src[1*stride];
    float v2 = scale * src[2*stride], v3 = scale * src[3*stride];
    float v4 = scale * src[4*stride], v5 = scale * src[5*stride];
    float v6 = scale * src[6*stride], v7 = scale * src[7*stride];
    a.u[0] = f2b2(v0, v1); a.u[1] = f2b2(v2, v3);
    a.u[2] = f2b2(v4, v5); a.u[3] = f2b2(v6, v7);
  } else {
    a.u[0] = 0; a.u[1] = 0; a.u[2] = 0; a.u[3] = 0;
  }
  *(short8*)(wsb + dest) = a.v;
}

// ---------------- main fused kernel ----------------
__global__ __launch_bounds__(256, 1)
void equiconv_main(const float* __restrict__ fea1,
                   const float* __restrict__ fea2,
                   const float* __restrict__ few,
                   const float* __restrict__ fb1,
                   const float* __restrict__ fb2,
                   const float* __restrict__ fb3,
                   const unsigned short* __restrict__ wsb,
                   float* __restrict__ out)
{
  __shared__ __align__(16) unsigned char pool[POOL_B];
  unsigned short* ring = (unsigned short*)pool;                 // 135,168B ring
  unsigned short* x1s_ = (unsigned short*)(pool + X1S_OFF);     // 32*66*2
  unsigned short* x1v_ = (unsigned short*)(pool + X1V_OFF);     // 32*98*2
  unsigned short* hb_  = (unsigned short*)(pool + X1S_OFF);     // alias x1 (dead post-K)
  float*          redf = (float*)pool;                          // alias ring (dead post-K)

  #define X1S(r, cc) x1s_[(r)*66 + (cc)]
  #define X1V(r, cc) x1v_[(r)*98 + (cc)]
  #define HB(w, r, cc) hb_[(((w)<<4) + (r))*72 + (cc)]

  const int tid  = threadIdx.x;
  const int lane = tid & 63, wv = tid >> 6;
  const int ln   = lane & 15, quad = lane >> 4, q8 = quad << 3;
  const int ebase = blockIdx.x << 5;          // 625 * 32 == 20000 exactly

  // ---- stage x1 (32 edges) into LDS as bf16 ----
  for (int it = tid; it < 1280; it += 256){
    int row = it / 40, seg = it - row*40;
    float4 v1 = *(const float4*)(fea1 + (size_t)(ebase + row)*160 + seg*4);
    const float* p1 = (const float*)&v1;
    int c0 = seg*4;
    #pragma unroll
    for (int jj = 0; jj < 4; jj++){
      int col = c0 + jj;
      if (col < 64) X1S(row, col) = f2b(p1[jj]);
      else          X1V(row, col-64) = f2b(p1[jj]);
    }
  }
  __syncthreads();

  // ---- hoist per-lane x2 fragments for both sub-tiles (direct from global) ----
  float xe[2][8], xo[2][8], y0[2][8], y1[2][8], y2[2][8];
  #pragma unroll
  for (int s = 0; s < 2; s++){
    const float* p = fea2 + (size_t)(ebase + s*16 + ln)*160;
    float4 a0 = *(const float4*)(p + q8);
    float4 a1 = *(const float4*)(p + q8 + 4);
    float4 b0 = *(const float4*)(p + 32 + q8);
    float4 b1 = *(const float4*)(p + 36 + q8);
    xe[s][0]=a0.x; xe[s][1]=a0.y; xe[s][2]=a0.z; xe[s][3]=a0.w;
    xe[s][4]=a1.x; xe[s][5]=a1.y; xe[s][6]=a1.z; xe[s][7]=a1.w;
    xo[s][0]=b0.x; xo[s][1]=b0.y; xo[s][2]=b0.z; xo[s][3]=b0.w;
    xo[s][4]=b1.x; xo[s][5]=b1.y; xo[s][6]=b1.z; xo[s][7]=b1.w;
    const float* py = p + 64 + q8*3;
    float yb[24];
    #pragma unroll
    for (int t = 0; t < 12; t++){
      float2 f2v = *(const float2*)(py + 2*t);
      yb[2*t] = f2v.x; yb[2*t+1] = f2v.y;
    }
    #pragma unroll
    for (int j = 0; j < 8; j++){
      y0[s][j] = yb[3*j]; y1[s][j] = yb[3*j+1]; y2[s][j] = yb[3*j+2];
    }
  }

  // ---- wave-private deep ring: 11 slots x 3KB, depth-10 prefetch ----
  const unsigned short* gstream = wsb + (size_t)wv*STRIDE_W;
  const int rbase = wv*NSLOT*HALF_USH;        // ushort offset of this wave's slots
  auto issue_half = [&](int h){
    const unsigned short* g = gstream + h*HALF_USH + lane*8;
    unsigned short* l = &ring[rbase + (h%NSLOT)*HALF_USH];
    #pragma unroll
    for (int q = 0; q < 3; q++)
      __builtin_amdgcn_global_load_lds(
        (const __attribute__((address_space(1))) unsigned int*)(g + q*FRAG_USH),
        (__attribute__((address_space(3))) unsigned int*)(l + q*FRAG_USH),
        16, 0, 0);
  };
  #pragma unroll
  for (int h = 0; h < 10; h++) issue_half(h);  // prime: 30 outstanding

  const int r0 = ln, r1 = 16 + ln;            // x1 rows for sub0/sub1
  const f32x4 z4 = {0.f,0.f,0.f,0.f};
  f32x4 accS[2][6] = {{z4,z4,z4,z4,z4,z4},{z4,z4,z4,z4,z4,z4}};
  f32x4 accV[2][3][2] = {{{z4,z4},{z4,z4},{z4,z4}},{{z4,z4},{z4,z4},{z4,z4}}};

  // One counted wait per half-step. Slot h%11; DMA(h+10) overwrites slot
  // (h-1)%11 whose reads retired via the lgkm waits before step h-1's MFMAs
  // (program order + sched_barrier pinning) -> timing-independent, no WAITL0.
  #define RSTEP(hh, bb, WCODE, DOISS) { \
    const int h_ = (hh); \
    WV(WCODE); \
    { const unsigned short* sl_ = &ring[rbase + (h_%NSLOT)*HALF_USH + lane*8]; \
      _Pragma("unroll") for (int t_ = 0; t_ < 3; t_++) bb[t_] = *(const short8*)(sl_ + t_*FRAG_USH); } \
    __builtin_amdgcn_sched_barrier(0); \
    if (DOISS) issue_half(h_ + 10); }

  // ===== SS: chunks 0..31 (halves 0..63); c = 2*u16 + half =====
  #pragma unroll 2
  for (int c = 0; c < 32; c++){
    int u = (wv<<4) + (c>>1);
    float s0 = b2f(X1S(r0, u));
    float s1 = b2f(X1S(r1, u));
    U8 a0, a1;
    if (c & 1){ PACK8(a0, s0, xo[0]); PACK8(a1, s1, xo[1]); }
    else      { PACK8(a0, s0, xe[0]); PACK8(a1, s1, xe[1]); }
    short8 bb[3];
    RSTEP(2*c, bb, 0x4F7B, 1);
    #pragma unroll
    for (int t = 0; t < 3; t++){
      accS[0][t] = mfma16(a0.v, bb[t], accS[0][t]);
      accS[1][t] = mfma16(a1.v, bb[t], accS[1][t]);
    }
    RSTEP(2*c+1, bb, 0x4F7B, 1);
    #pragma unroll
    for (int t = 0; t < 3; t++){
      accS[0][3+t] = mfma16(a0.v, bb[t], accS[0][3+t]);
      accS[1][3+t] = mfma16(a1.v, bb[t], accS[1][3+t]);
    }
  }
  // ===== VV: chunks 32..39 (halves 64..79); one u per chunk =====
  #pragma unroll 1
  for (int k8 = 0; k8 < 8; k8++){
    int c = 32 + k8, u = (wv<<3) + k8;
    U8 a[2];
    #pragma unroll
    for (int s = 0; s < 2; s++){
      int rr = s ? r1 : r0;
      float c0 = b2f(X1V(rr, u*3+0));
      float c1 = b2f(X1V(rr, u*3+1));
      float c2 = b2f(X1V(rr, u*3+2));
      float pv[8];
      #pragma unroll
      for (int j = 0; j < 8; j++)
        pv[j] = c0*y0[s][j] + c1*y1[s][j] + c2*y2[s][j];
      a[s].u[0]=f2b2(pv[0],pv[1]); a[s].u[1]=f2b2(pv[2],pv[3]);
      a[s].u[2]=f2b2(pv[4],pv[5]); a[s].u[3]=f2b2(pv[6],pv[7]);
    }
    short8 bb[3];
    RSTEP(2*c, bb, 0x4F7B, 1);
    #pragma unroll
    for (int t = 0; t < 3; t++){
      accS[0][t] = mfma16(a[0].v, bb[t], accS[0][t]);
      accS[1][t] = mfma16(a[1].v, bb[t], accS[1][t]);
    }
    RSTEP(2*c+1, bb, 0x4F7B, 1);
    #pragma unroll
    for (int t = 0; t < 3; t++){
      accS[0][3+t] = mfma16(a[0].v, bb[t], accS[0][3+t]);
      accS[1][3+t] = mfma16(a[1].v, bb[t], accS[1][3+t]);
    }
  }
  // ===== SV: chunks 40..45 (halves 80..91); frag f=(uu=f>>1, tp=f&1) =====
  #pragma unroll 1
  for (int ch = 0; ch < 6; ch++){
    int c = 40 + ch;
    int u0 = (wv<<4) + ch*3;
    short8 bb[3];
    RSTEP(2*c, bb, 0x4F7B, 1);
    {
      float s0 = b2f(X1S(r0, u0)), s1 = b2f(X1S(r1, u0));
      U8 a[2][3];
      PACK8(a[0][0], s0, y0[0]); PACK8(a[0][1], s0, y1[0]); PACK8(a[0][2], s0, y2[0]);
      PACK8(a[1][0], s1, y0[1]); PACK8(a[1][1], s1, y1[1]); PACK8(a[1][2], s1, y2[1]);
      #pragma unroll
      for (int s = 0; s < 2; s++)
        #pragma unroll
        for (int i = 0; i < 3; i++){
          accV[s][i][0] = mfma16(a[s][i].v, bb[0], accV[s][i][0]);   // f0: (u0,tp0)
          accV[s][i][1] = mfma16(a[s][i].v, bb[1], accV[s][i][1]);   // f1: (u0,tp1)
        }
      if (ch < 5){                                                   // u1 = ui ch*3+1 < 16
        float t0v = b2f(X1S(r0, u0+1)), t1v = b2f(X1S(r1, u0+1));
        U8 b[2][3];
        PACK8(b[0][0], t0v, y0[0]); PACK8(b[0][1], t0v, y1[0]); PACK8(b[0][2], t0v, y2[0]);
        PACK8(b[1][0], t1v, y0[1]); PACK8(b[1][1], t1v, y1[1]); PACK8(b[1][2], t1v, y2[1]);
        #pragma unroll
        for (int s = 0; s < 2; s++)
          #pragma unroll
          for (int i = 0; i < 3; i++)
            accV[s][i][0] = mfma16(b[s][i].v, bb[2], accV[s][i][0]); // f2: (u1,tp0)
      }
    }
    RSTEP(2*c+1, bb, 0x4F7B, 1);
    if (ch < 5){
      float t0v = b2f(X1S(r0, u0+1)), t1v = b2f(X1S(r1, u0+1));
      U8 b[2][3];
      PACK8(b[0][0], t0v, y0[0]); PACK8(b[0][1], t0v, y1[0]); PACK8(b[0][2], t0v, y2[0]);
      PACK8(b[1][0], t1v, y0[1]); PACK8(b[1][1], t1v, y1[1]); PACK8(b[1][2], t1v, y2[1]);
      #pragma unroll
      for (int s = 0; s < 2; s++)
        #pragma unroll
        for (int i = 0; i < 3; i++)
          accV[s][i][1] = mfma16(b[s][i].v, bb[0], accV[s][i][1]);   // f3: (u1,tp1)
      float v0 = b2f(X1S(r0, u0+2)), v1s = b2f(X1S(r1, u0+2));
      U8 d[2][3];
      PACK8(d[0][0], v0, y0[0]);  PACK8(d[0][1], v0, y1[0]);  PACK8(d[0][2], v0, y2[0]);
      PACK8(d[1][0], v1s, y0[1]); PACK8(d[1][1], v1s, y1[1]); PACK8(d[1][2], v1s, y2[1]);
      #pragma unroll
      for (int s = 0; s < 2; s++)
        #pragma unroll
        for (int i = 0; i < 3; i++){
          accV[s][i][0] = mfma16(d[s][i].v, bb[1], accV[s][i][0]);   // f4: (u2,tp0)
          accV[s][i][1] = mfma16(d[s][i].v, bb[2], accV[s][i][1]);   // f5: (u2,tp1)
        }
    }
  }
  // ===== VS: chunks 46..51 (halves 92..103); explicit tail drain ladder =====
  #define VSPC(pcv, W0, DI0, W1, DI1) { \
    const int p_ = (pcv)/3, ch_ = (pcv)%3, c_ = 46+(pcv); \
    const int u0_ = (wv<<3) + ch_*3; \
    short8 bb[3]; \
    RSTEP(2*c_, bb, W0, DI0); \
    { U8 a_[2][3]; \
      _Pragma("unroll") for (int s_ = 0; s_ < 2; s_++){ \
        int rr_ = s_ ? r1 : r0; \
        float c0_ = b2f(X1V(rr_, u0_*3+0)), c1_ = b2f(X1V(rr_, u0_*3+1)), c2_ = b2f(X1V(rr_, u0_*3+2)); \
        const float* xx_ = p_ ? xo[s_] : xe[s_]; \
        PACK8(a_[s_][0], c0_, xx_); PACK8(a_[s_][1], c1_, xx_); PACK8(a_[s_][2], c2_, xx_); } \
      _Pragma("unroll") for (int s_ = 0; s_ < 2; s_++) \
        _Pragma("unroll") for (int i_ = 0; i_ < 3; i_++){ \
          accV[s_][i_][0] = mfma16(a_[s_][i_].v, bb[0], accV[s_][i_][0]); \
          accV[s_][i_][1] = mfma16(a_[s_][i_].v, bb[1], accV[s_][i_][1]); } \
      U8 b_[2][3]; \
      _Pragma("unroll") for (int s_ = 0; s_ < 2; s_++){ \
        int rr_ = s_ ? r1 : r0; \
        float c0_ = b2f(X1V(rr_, (u0_+1)*3+0)), c1_ = b2f(X1V(rr_, (u0_+1)*3+1)), c2_ = b2f(X1V(rr_, (u0_+1)*3+2)); \
        const float* xx_ = p_ ? xo[s_] : xe[s_]; \
        PACK8(b_[s_][0], c0_, xx_); PACK8(b_[s_][1], c1_, xx_); PACK8(b_[s_][2], c2_, xx_); } \
      _Pragma("unroll") for (int s_ = 0; s_ < 2; s_++) \
        _Pragma("unroll") for (int i_ = 0; i_ < 3; i_++) \
          accV[s_][i_][0] = mfma16(b_[s_][i_].v, bb[2], accV[s_][i_][0]); } \
    RSTEP(2*c_+1, bb, W1, DI1); \
    { U8 b_[2][3]; \
      _Pragma("unroll") for (int s_ = 0; s_ < 2; s_++){ \
        int rr_ = s_ ? r1 : r0; \
        float c0_ = b2f(X1V(rr_, (u0_+1)*3+0)), c1_ = b2f(X1V(rr_, (u0_+1)*3+1)), c2_ = b2f(X1V(rr_, (u0_+1)*3+2)); \
        const float* xx_ = p_ ? xo[s_] : xe[s_]; \
        PACK8(b_[s_][0], c0_, xx_); PACK8(b_[s_][1], c1_, xx_); PACK8(b_[s_][2], c2_, xx_); } \
      _Pragma("unroll") for (int s_ = 0; s_ < 2; s_++) \
        _Pragma("unroll") for (int i_ = 0; i_ < 3; i_++) \
          accV[s_][i_][1] = mfma16(b_[s_][i_].v, bb[0], accV[s_][i_][1]); \
      if (ch_ < 2){ \
        U8 d_[2][3]; \
        _Pragma("unroll") for (int s_ = 0; s_ < 2; s_++){ \
          int rr_ = s_ ? r1 : r0; \
          float c0_ = b2f(X1V(rr_, (u0_+2)*3+0)), c1_ = b2f(X1V(rr_, (u0_+2)*3+1)), c2_ = b2f(X1V(rr_, (u0_+2)*3+2)); \
          const float* xx_ = p_ ? xo[s_] : xe[s_]; \
          PACK8(d_[s_][0], c0_, xx_); PACK8(d_[s_][1], c1_, xx_); PACK8(d_[s_][2], c2_, xx_); } \
        _Pragma("unroll") for (int s_ = 0; s_ < 2; s_++) \
          _Pragma("unroll") for (int i_ = 0; i_ < 3; i_++){ \
            accV[s_][i_][0] = mfma16(d_[s_][i_].v, bb[1], accV[s_][i_][0]); \
            accV[s_][i_][1] = mfma16(d_[s_][i_].v, bb[2], accV[s_][i_][1]); } } } }

  VSPC(0, 0x4F7B, 1, 0x4F7B, 1);   // h92 (issue 102), h93 (issue 103)
  VSPC(1, 0x4F7B, 0, 0x4F78, 0);   // h94 w27, h95 w24
  VSPC(2, 0x4F75, 0, 0x4F72, 0);   // h96 w21, h97 w18
  VSPC(3, 0x0F7F, 0, 0x0F7C, 0);   // h98 w15, h99 w12
  VSPC(4, 0x0F79, 0, 0x0F76, 0);   // h100 w9, h101 w6
  VSPC(5, 0x0F73, 0, 0x0F70, 0);   // h102 w3, h103 w0 (full drain)

  // ---- gather partials: T0 = sub0's 12 tiles, T1 = sub1's ----
  f32x4 T0[12], T1[12];
  #pragma unroll
  for (int t = 0; t < 6; t++){ T0[t] = accS[0][t]; T1[t] = accS[1][t]; }
  #pragma unroll
  for (int t = 0; t < 2; t++)
    #pragma unroll
    for (int i = 0; i < 3; i++){
      T0[6+3*t+i] = accV[0][i][t]; T1[6+3*t+i] = accV[1][i][t];
    }

  // ---- cross-wave K-reduction through reused ring (A=slots0-11, B=12-23) ----
  #define PUT12(base, T) { _Pragma("unroll") for (int j=0;j<12;j++) \
    *(f32x4*)(redf + ((base)+j)*320 + ln*20 + (quad<<2)) = T[j]; }
  #define ADD12(base, T) { _Pragma("unroll") for (int j=0;j<12;j++) \
    T[j] += *(const f32x4*)(redf + ((base)+j)*320 + ln*20 + (quad<<2)); }

  __syncthreads();                               // all waves drained own DMA (w0 at h103)
  if (wv==1) PUT12(0, T0);  if (wv==2) PUT12(12, T1);
  __syncthreads();
  if (wv==0) ADD12(0, T0);  if (wv==3) ADD12(12, T1);
  __syncthreads();
  if (wv==2) PUT12(0, T0);  if (wv==1) PUT12(12, T1);
  __syncthreads();
  if (wv==0) ADD12(0, T0);  if (wv==3) ADD12(12, T1);
  __syncthreads();
  if (wv==3) PUT12(0, T0);  if (wv==0) PUT12(12, T1);
  __syncthreads();
  if (wv==0) ADD12(0, T0);  if (wv==3) ADD12(12, T1);
  // w0 now owns final sub0 tiles in T0; w3 owns final sub1 in T1.

  if (wv == 1 || wv == 2) return;
  const int s = (wv == 0) ? 0 : 1;
  f32x4* P = (wv == 0) ? T0 : T1;

  // ---- FC chain (owner wave, wave-private h buffer aliased on x1 region) ----
  f32x4 accF[4] = {z4,z4,z4,z4};
  {
    const float* fwp = few + (size_t)(ebase + s*16 + ln)*128;
    const short8* B = (const short8*)(wsb + FC1_OFF);
    #pragma unroll
    for (int c = 0; c < 4; c++){
      float4 fa  = *(const float4*)(fwp + c*32 + q8);
      float4 fbv = *(const float4*)(fwp + c*32 + q8 + 4);
      U8 a;
      a.u[0]=f2b2(fa.x,fa.y);   a.u[1]=f2b2(fa.z,fa.w);
      a.u[2]=f2b2(fbv.x,fbv.y); a.u[3]=f2b2(fbv.z,fbv.w);
      #pragma unroll
      for (int t = 0; t < 4; t++) accF[t] = mfma16(a.v, B[(c*4+t)*64 + lane], accF[t]);
    }
  }
  #pragma unroll
  for (int t = 0; t < 4; t++){
    float bb = fb1[(t<<4)+ln];
    #pragma unroll
    for (int r = 0; r < 4; r++)
      HB(wv, (quad<<2)+r, (t<<4)+ln) = f2b(silu_f(accF[t][r] + bb));
  }
  f32x4 acc2[4] = {z4,z4,z4,z4};
  {
    const short8* B = (const short8*)(wsb + FC2_OFF);
    #pragma unroll
    for (int c = 0; c < 2; c++){
      uint4 hq = *(const uint4*)&HB(wv, ln, c*32 + q8);
      U8 a; a.u[0]=hq.x; a.u[1]=hq.y; a.u[2]=hq.z; a.u[3]=hq.w;
      #pragma unroll
      for (int t = 0; t < 4; t++) acc2[t] = mfma16(a.v, B[(c*4+t)*64 + lane], acc2[t]);
    }
  }
  #pragma unroll
  for (int t = 0; t < 4; t++){
    float bb = fb2[(t<<4)+ln];
    #pragma unroll
    for (int r = 0; r < 4; r++)
      HB(wv, (quad<<2)+r, (t<<4)+ln) = f2b(silu_f(acc2[t][r] + bb));
  }
  f32x4 acc3[6] = {z4,z4,z4,z4,z4,z4};
  {
    const short8* B = (const short8*)(wsb + FC3_OFF);
    #pragma unroll
    for (int c = 0; c < 2; c++){
      uint4 hq = *(const uint4*)&HB(wv, ln, c*32 + q8);
      U8 a; a.u[0]=hq.x; a.u[1]=hq.y; a.u[2]=hq.z; a.u[3]=hq.w;
      #pragma unroll
      for (int t = 0; t < 6; t++) acc3[t] = mfma16(a.v, B[(c*6+t)*64 + lane], acc3[t]);
    }
  }

  // ---- epilogue (C-layout row = quad*4+r; 625*32 = 20000, no guards) ----
  #pragma unroll
  for (int r = 0; r < 4; r++){
    int eg = ebase + s*16 + (quad<<2) + r;
    float* op = out + (size_t)eg*160;
    #pragma unroll
    for (int t = 0; t < 4; t++)
      op[(t<<4)+ln] = silu_f(P[t][r]) * (acc3[t][r] + fb3[(t<<4)+ln]);
    #pragma unroll
    for (int tp = 0; tp < 2; tp++){
      int wc = (tp<<4) + ln;
      float f = sigm_f(P[4+tp][r]) * (acc3[4+tp][r] + fb3[64+wc]);
      op[64 + wc*3 + 0] = P[6+3*tp+0][r] * f;
      op[64 + wc*3 + 1] = P[6+3*tp+1][r] * f;
      op[64 + wc*3 + 2] = P[6+3*tp+2][r] * f;
    }
  }
}

extern "C" void kernel_launch(void* const* d_in, const int* in_sizes, int n_in,
                              void* d_out, int out_size, void* d_ws, size_t ws_size,
                              hipStream_t stream) {
  (void)in_sizes; (void)n_in; (void)out_size; (void)ws_size;
  unsigned short* wsb = (unsigned short*)d_ws;

  prep_weights<<<(WS_USH/8 + 255)/256, 256, 0, stream>>>(
      (const float*)d_in[3], (const float*)d_in[5],     // ss_s, ss_g
      (const float*)d_in[4], (const float*)d_in[6],     // vv_s, vv_g
      (const float*)d_in[7], (const float*)d_in[8],     // sv, vs
      (const float*)d_in[9], (const float*)d_in[11], (const float*)d_in[13],
      wsb);

  equiconv_main<<<E_TOT/32, 256, 0, stream>>>(
      (const float*)d_in[0], (const float*)d_in[1], (const float*)d_in[2],
      (const float*)d_in[10], (const float*)d_in[12], (const float*)d_in[14],
      (const unsigned short*)wsb, (float*)d_out);
}

// Round 4
// 176.096 us; speedup vs baseline: 1.2378x; 1.2378x over previous
//
#include <hip/hip_runtime.h>

// EquiConv fused MFMA kernel for MI355X (gfx950) — round 9.
// R8 post-mortem: depth-10 ring at 1 block/CU regressed 2.1x (MfmaUtil 16->7.5,
// same MFMA cycles) -> TLP (8 waves/CU) was hiding the stalls; per-wave depth
// can't substitute. Regs (124+96acc) cap 2 waves/SIMD, so occupancy is fixed.
// R9 = R7's exact compute + occupancy, with the per-step serialization removed:
// 5 half-chunk slots/wave (3KB each, 60KB ring total, 71.9KB LDS/block with hb
// aliased onto dead x1 -> still 2 blocks/CU), same 12KB/wave in-flight depth,
// finer waits: vmcnt(9) per half (consume half 0 while half 1 in flight),
// lgkmcnt(3) overwrite guard instead of full lgkm drain. Compute bodies and
// accumulation order byte-identical to R7 -> absmax canary 0.09375 expected.
// prep_weights unchanged from R7 (dest-linear gather).

#define E_TOT 20000

typedef __attribute__((ext_vector_type(8))) short short8;
typedef __attribute__((ext_vector_type(4))) float f32x4;
typedef __attribute__((ext_vector_type(2))) __bf16 bf16x2;

#define FRAG_USH 512
#define HALF_USH 1536          // 3 frags = 3KB (ring slot)
#define CH_USH   3072          // 6 frags = 6KB (stream layout unit)
#define N_CH     52
#define NSLOT    5             // ring slots per wave (5 x 3KB = 15KB/wave)
#define STRIDE_W 159744        // 312 frags * 512 ushort per wave stream
#define FC1_OFF  638976        // 4*STRIDE_W
#define FC2_OFF  647168
#define FC3_OFF  651264
#define WS_USH   657408        // 1.28 MB of d_ws

// LDS pool carve (bytes): ring 61440 + x1s 4224 + x1v 6272 = 71936 (<81920 -> 2 blk/CU)
#define X1S_OFF  61440
#define X1V_OFF  65664
#define POOL_B   71936

__device__ __forceinline__ unsigned short f2b(float f){
  return __builtin_bit_cast(unsigned short, (__bf16)f);
}
__device__ __forceinline__ unsigned f2b2(float lo, float hi){
  bf16x2 t; t[0] = (__bf16)lo; t[1] = (__bf16)hi;
  return __builtin_bit_cast(unsigned, t);
}
__device__ __forceinline__ float b2f(unsigned short h){
  return __uint_as_float(((unsigned)h) << 16);
}
__device__ __forceinline__ f32x4 mfma16(short8 a, short8 b, f32x4 c){
  return __builtin_amdgcn_mfma_f32_16x16x32_bf16(a, b, c, 0, 0, 0);
}
union U8 { short8 v; unsigned u[4]; };
__device__ __forceinline__ float silu_f(float x){ return x/(1.f+__expf(-x)); }
__device__ __forceinline__ float sigm_f(float x){ return 1.f/(1.f+__expf(-x)); }

#define PACK8(a, s, x) \
  a.u[0]=f2b2((s)*(x)[0],(s)*(x)[1]); a.u[1]=f2b2((s)*(x)[2],(s)*(x)[3]); \
  a.u[2]=f2b2((s)*(x)[4],(s)*(x)[5]); a.u[3]=f2b2((s)*(x)[6],(s)*(x)[7]);

// s_waitcnt simm16: vmcnt[3:0]|[15:14], expcnt[6:4], lgkmcnt[11:8]
// vmcnt(9)=0x0F79 vmcnt(6)=0x0F76 vmcnt(3)=0x0F73 vmcnt(0)=0x0F70
// lgkmcnt(3), vmcnt nowait = 0xC37F
#define WV(code) { __builtin_amdgcn_s_waitcnt(code); __builtin_amdgcn_sched_barrier(0); }
#define WL3      { __builtin_amdgcn_s_waitcnt(0xC37F); __builtin_amdgcn_sched_barrier(0); }

// dest position of (k_local, n16) inside a 512-ushort fragment
__device__ __forceinline__ int fpos(int kl, int n16){
  return (kl>>3)*128 + n16*8 + (kl&7);
}

// ---------------- prep: dest-linear gather into per-wave streams ----------------
__global__ void prep_weights(const float* __restrict__ ss_s, const float* __restrict__ ss_g,
                             const float* __restrict__ vv_s, const float* __restrict__ vv_g,
                             const float* __restrict__ sv,   const float* __restrict__ vs,
                             const float* __restrict__ w1,   const float* __restrict__ w2,
                             const float* __restrict__ w3,   unsigned short* __restrict__ wsb)
{
  int g = blockIdx.x * 256 + threadIdx.x;
  if (g >= WS_USH/8) return;
  const int dest = g << 3;
  const float A_SC  = 0.013975424859373686f;                     // 1/sqrt(S*S+V*V)
  const float A_VV  = (float)(0.013975424859373686 * 0.5773502691896258);
  const float A_VEC = 0.015625f;                                 // 1/sqrt(2*S*V)

  const float* src = nullptr;
  int stride = 0;
  float scale = 1.f;

  if (dest < FC1_OFF) {                      // 4 per-wave streams
    int wave = dest / STRIDE_W;
    int off  = dest - wave*STRIDE_W;
    int c    = off / CH_USH;
    int rem  = off - c*CH_USH;
    int t    = rem >> 9;                     // fragment 0..5
    int p    = rem & 511;
    int kl   = (p >> 7) << 3;                // base kl; +j inside group
    int n16  = (p >> 3) & 15;
    if (c < 32) {                            // SS: ss_s (t0..3) + ss_g (t4,5)
      int u = (wave<<4) + (c>>1);
      int v = ((c&1)<<5) + kl;
      if (t < 4) { src = ss_s + (u<<12)+(v<<6)+((t<<4)+n16);     stride = 64; }
      else       { src = ss_g + (u<<11)+(v<<5)+(((t-4)<<4)+n16); stride = 32; }
      scale = A_SC;
    } else if (c < 40) {                     // VV: vv_s (t0..3) + vv_g (t4,5)
      int u = (wave<<3) + (c-32);
      int v = kl;
      if (t < 4) { src = vv_s + (u<<11)+(v<<6)+((t<<4)+n16);     stride = 64; }
      else       { src = vv_g + (u<<10)+(v<<5)+(((t-4)<<4)+n16); stride = 32; }
      scale = A_VV;
    } else if (c < 46) {                     // SV: chunks 40..45, ul = ch*3 + t/2
      int ul = (c-40)*3 + (t>>1);
      if (ul < 16) {
        int u = (wave<<4) + ul;
        src = sv + (u<<10)+(kl<<5)+(((t&1)<<4)+n16);
        stride = 32; scale = A_VEC;
      }                                      // else: gap frag (c=45,t>=2) -> 0
    } else {                                 // VS: chunks 46..51
      int cc = c - 46;
      int vh = cc/3, ch3 = cc - vh*3;
      int fseq = ch3*6 + t;
      if (fseq < 16) {
        int u = (wave<<3) + (fseq>>1);
        int v = (vh<<5) + kl;
        src = vs + (u<<11)+(v<<5)+(((fseq&1)<<4)+n16);
        stride = 32; scale = A_VEC;
      }                                      // else: gap frag (ch3=2,t>=4) -> 0
    }
  } else if (dest < FC2_OFF) {               // fc1 [128][64]
    int off = dest - FC1_OFF;
    int fi = off >> 9, p = off & 511;
    int kl = (p>>7)<<3, n16 = (p>>3)&15;
    int k = ((fi>>2)<<5) + kl, n = ((fi&3)<<4) + n16;
    src = w1 + (k<<6) + n; stride = 64;
  } else if (dest < FC3_OFF) {               // fc2 [64][64]
    int off = dest - FC2_OFF;
    int fi = off >> 9, p = off & 511;
    int kl = (p>>7)<<3, n16 = (p>>3)&15;
    int k = ((fi>>2)<<5) + kl, n = ((fi&3)<<4) + n16;
    src = w2 + (k<<6) + n; stride = 64;
  } else {                                   // fc3 [64][96]
    int off = dest - FC3_OFF;
    int fi = off >> 9, p = off & 511;
    int kl = (p>>7)<<3, n16 = (p>>3)&15;
    int koff = fi/6, nhi = fi - koff*6;
    int k = (koff<<5) + kl, n = (nhi<<4) + n16;
    src = w3 + k*96 + n; stride = 96;
  }

  U8 a;
  if (src) {
    float v0 = scale * src[0*stride], v1 = scale * src[1*stride];
    float v2 = scale * src[2*stride], v3 = scale * src[3*stride];
    float v4 = scale * src[4*stride], v5 = scale * src[5*stride];
    float v6 = scale * src[6*stride], v7 = scale * src[7*stride];
    a.u[0] = f2b2(v0, v1); a.u[1] = f2b2(v2, v3);
    a.u[2] = f2b2(v4, v5); a.u[3] = f2b2(v6, v7);
  } else {
    a.u[0] = 0; a.u[1] = 0; a.u[2] = 0; a.u[3] = 0;
  }
  *(short8*)(wsb + dest) = a.v;
}

// ---------------- main fused kernel ----------------
__global__ __launch_bounds__(256, 2)
void equiconv_main(const float* __restrict__ fea1,
                   const float* __restrict__ fea2,
                   const float* __restrict__ few,
                   const float* __restrict__ fb1,
                   const float* __restrict__ fb2,
                   const float* __restrict__ fb3,
                   const unsigned short* __restrict__ wsb,
                   float* __restrict__ out)
{
  __shared__ __align__(16) unsigned char pool[POOL_B];
  unsigned short* ring = (unsigned short*)pool;                 // 61440B ring
  unsigned short* x1s_ = (unsigned short*)(pool + X1S_OFF);     // 32*66*2
  unsigned short* x1v_ = (unsigned short*)(pool + X1V_OFF);     // 32*98*2
  unsigned short* hb_  = (unsigned short*)(pool + X1S_OFF);     // alias x1 (dead post-K)
  float*          redf = (float*)pool;                          // alias ring (dead post-K)

  #define X1S(r, cc) x1s_[(r)*66 + (cc)]
  #define X1V(r, cc) x1v_[(r)*98 + (cc)]
  #define HB(w, r, cc) hb_[(((w)<<4) + (r))*72 + (cc)]

  const int tid  = threadIdx.x;
  const int lane = tid & 63, wv = tid >> 6;
  const int ln   = lane & 15, quad = lane >> 4, q8 = quad << 3;
  const int ebase = blockIdx.x << 5;          // 625 * 32 == 20000 exactly

  // ---- stage x1 (32 edges) into LDS as bf16 ----
  for (int it = tid; it < 1280; it += 256){
    int row = it / 40, seg = it - row*40;
    float4 v1 = *(const float4*)(fea1 + (size_t)(ebase + row)*160 + seg*4);
    const float* p1 = (const float*)&v1;
    int c0 = seg*4;
    #pragma unroll
    for (int jj = 0; jj < 4; jj++){
      int col = c0 + jj;
      if (col < 64) X1S(row, col) = f2b(p1[jj]);
      else          X1V(row, col-64) = f2b(p1[jj]);
    }
  }
  __syncthreads();

  // ---- hoist per-lane x2 fragments for both sub-tiles (direct from global) ----
  float xe[2][8], xo[2][8], y0[2][8], y1[2][8], y2[2][8];
  #pragma unroll
  for (int s = 0; s < 2; s++){
    const float* p = fea2 + (size_t)(ebase + s*16 + ln)*160;
    float4 a0 = *(const float4*)(p + q8);
    float4 a1 = *(const float4*)(p + q8 + 4);
    float4 b0 = *(const float4*)(p + 32 + q8);
    float4 b1 = *(const float4*)(p + 36 + q8);
    xe[s][0]=a0.x; xe[s][1]=a0.y; xe[s][2]=a0.z; xe[s][3]=a0.w;
    xe[s][4]=a1.x; xe[s][5]=a1.y; xe[s][6]=a1.z; xe[s][7]=a1.w;
    xo[s][0]=b0.x; xo[s][1]=b0.y; xo[s][2]=b0.z; xo[s][3]=b0.w;
    xo[s][4]=b1.x; xo[s][5]=b1.y; xo[s][6]=b1.z; xo[s][7]=b1.w;
    const float* py = p + 64 + q8*3;
    float yb[24];
    #pragma unroll
    for (int t = 0; t < 12; t++){
      float2 f2v = *(const float2*)(py + 2*t);
      yb[2*t] = f2v.x; yb[2*t+1] = f2v.y;
    }
    #pragma unroll
    for (int j = 0; j < 8; j++){
      y0[s][j] = yb[3*j]; y1[s][j] = yb[3*j+1]; y2[s][j] = yb[3*j+2];
    }
  }

  // ---- wave-private ring: 5 slots x 3KB, 4 halves (12KB) in flight ----
  const unsigned short* gstream = wsb + (size_t)wv*STRIDE_W;
  const int rbase = wv*NSLOT*HALF_USH;        // ushort offset of this wave's slots
  auto issue_half = [&](int h){
    const unsigned short* g = gstream + h*HALF_USH + lane*8;
    unsigned short* l = &ring[rbase + (h%NSLOT)*HALF_USH];
    #pragma unroll
    for (int q = 0; q < 3; q++)
      __builtin_amdgcn_global_load_lds(
        (const __attribute__((address_space(1))) unsigned int*)(g + q*FRAG_USH),
        (__attribute__((address_space(3))) unsigned int*)(l + q*FRAG_USH),
        16, 0, 0);
  };
  issue_half(0); issue_half(1); issue_half(2); issue_half(3);  // prime: 12 loads

  const int r0 = ln, r1 = 16 + ln;            // x1 rows for sub0/sub1
  const f32x4 z4 = {0.f,0.f,0.f,0.f};
  f32x4 accS[2][6] = {{z4,z4,z4,z4,z4,z4},{z4,z4,z4,z4,z4,z4}};
  f32x4 accV[2][3][2] = {{{z4,z4},{z4,z4},{z4,z4}},{{z4,z4},{z4,z4},{z4,z4}}};

  // Per-chunk read: two half-waits. Steady state: outstanding = halves
  // {2c..2c+3} = 12 loads. W vmcnt(9) -> half 2c arrived; read it; issue 2c+4
  // (slot of half 2c-1, whose ds_reads retired before chunk c-1's MFMAs).
  // W vmcnt(9) -> half 2c+1 arrived; read it; lgkmcnt(3) -> half 2c's 3
  // ds_reads retired (in-order); issue 2c+5 (overwrites half 2c's slot).
  #define READCH(cc, bb, WAC, WBC, DOISS) { \
    const int h0_ = 2*(cc); \
    const int sA_ = h0_ % NSLOT, sB_ = (h0_+1) % NSLOT; \
    WV(WAC); \
    { const unsigned short* pA_ = &ring[rbase + sA_*HALF_USH + lane*8]; \
      bb[0] = *(const short8*)(pA_); \
      bb[1] = *(const short8*)(pA_ + FRAG_USH); \
      bb[2] = *(const short8*)(pA_ + 2*FRAG_USH); } \
    __builtin_amdgcn_sched_barrier(0); \
    if (DOISS) issue_half(h0_ + 4); \
    WV(WBC); \
    { const unsigned short* pB_ = &ring[rbase + sB_*HALF_USH + lane*8]; \
      bb[3] = *(const short8*)(pB_); \
      bb[4] = *(const short8*)(pB_ + FRAG_USH); \
      bb[5] = *(const short8*)(pB_ + 2*FRAG_USH); } \
    __builtin_amdgcn_sched_barrier(0); \
    if (DOISS) { WL3; issue_half(h0_ + 5); } }

  // ===== SS: chunks 0..31; c = 2*u16 + half =====
  #pragma unroll 2
  for (int c = 0; c < 32; c++){
    int u = (wv<<4) + (c>>1);
    float s0 = b2f(X1S(r0, u));
    float s1 = b2f(X1S(r1, u));
    U8 a0, a1;
    if (c & 1){ PACK8(a0, s0, xo[0]); PACK8(a1, s1, xo[1]); }
    else      { PACK8(a0, s0, xe[0]); PACK8(a1, s1, xe[1]); }
    short8 bb[6];
    READCH(c, bb, 0x0F79, 0x0F79, 1);
    #pragma unroll
    for (int t = 0; t < 6; t++){
      accS[0][t] = mfma16(a0.v, bb[t], accS[0][t]);
      accS[1][t] = mfma16(a1.v, bb[t], accS[1][t]);
    }
  }
  // ===== VV: chunks 32..39; one u per chunk =====
  #pragma unroll 1
  for (int k8 = 0; k8 < 8; k8++){
    int c = 32 + k8, u = (wv<<3) + k8;
    U8 a[2];
    #pragma unroll
    for (int s = 0; s < 2; s++){
      int rr = s ? r1 : r0;
      float c0 = b2f(X1V(rr, u*3+0));
      float c1 = b2f(X1V(rr, u*3+1));
      float c2 = b2f(X1V(rr, u*3+2));
      float pv[8];
      #pragma unroll
      for (int j = 0; j < 8; j++)
        pv[j] = c0*y0[s][j] + c1*y1[s][j] + c2*y2[s][j];
      a[s].u[0]=f2b2(pv[0],pv[1]); a[s].u[1]=f2b2(pv[2],pv[3]);
      a[s].u[2]=f2b2(pv[4],pv[5]); a[s].u[3]=f2b2(pv[6],pv[7]);
    }
    short8 bb[6];
    READCH(c, bb, 0x0F79, 0x0F79, 1);
    #pragma unroll
    for (int t = 0; t < 6; t++){
      accS[0][t] = mfma16(a[0].v, bb[t], accS[0][t]);
      accS[1][t] = mfma16(a[1].v, bb[t], accS[1][t]);
    }
  }
  // ===== SV: chunks 40..45; 3 u per chunk, 2 frags each =====
  #pragma unroll 1
  for (int ch = 0; ch < 6; ch++){
    int c = 40 + ch;
    short8 bb[6];
    READCH(c, bb, 0x0F79, 0x0F79, 1);
    #pragma unroll
    for (int uu = 0; uu < 3; uu++){
      int ui = ch*3 + uu;
      if (ui < 16){
        int u = (wv<<4) + ui;
        float s0 = b2f(X1S(r0, u));
        float s1 = b2f(X1S(r1, u));
        U8 a[2][3];
        PACK8(a[0][0], s0, y0[0]); PACK8(a[0][1], s0, y1[0]); PACK8(a[0][2], s0, y2[0]);
        PACK8(a[1][0], s1, y0[1]); PACK8(a[1][1], s1, y1[1]); PACK8(a[1][2], s1, y2[1]);
        #pragma unroll
        for (int t = 0; t < 2; t++){
          short8 b8 = bb[uu*2 + t];
          #pragma unroll
          for (int s = 0; s < 2; s++)
            #pragma unroll
            for (int i = 0; i < 3; i++)
              accV[s][i][t] = mfma16(a[s][i].v, b8, accV[s][i][t]);
        }
      }
    }
  }
  // ===== VS: chunks 46..51; phase p (xe/xo), 3 u per chunk, 2 frags each =====
  #define VSBODY(pcv, bb) { \
    const int p_ = (pcv)/3, ch_ = (pcv) - p_*3; \
    _Pragma("unroll") \
    for (int uu = 0; uu < 3; uu++){ \
      int ui = ch_*3 + uu; \
      if (ui < 8){ \
        int u = (wv<<3) + ui; \
        U8 a[2][3]; \
        _Pragma("unroll") \
        for (int s = 0; s < 2; s++){ \
          int rr = s ? r1 : r0; \
          float c0 = b2f(X1V(rr, u*3+0)); \
          float c1 = b2f(X1V(rr, u*3+1)); \
          float c2 = b2f(X1V(rr, u*3+2)); \
          const float* xx = p_ ? xo[s] : xe[s]; \
          PACK8(a[s][0], c0, xx); PACK8(a[s][1], c1, xx); PACK8(a[s][2], c2, xx); \
        } \
        _Pragma("unroll") \
        for (int t = 0; t < 2; t++){ \
          short8 b8 = bb[uu*2 + t]; \
          _Pragma("unroll") \
          for (int s = 0; s < 2; s++) \
            _Pragma("unroll") \
            for (int i = 0; i < 3; i++) \
              accV[s][i][t] = mfma16(a[s][i].v, b8, accV[s][i][t]); \
        } \
      } \
    } }

  #pragma unroll 1
  for (int pc = 0; pc < 4; pc++){            // chunks 46..49: normal issue
    short8 bb[6];
    READCH(46+pc, bb, 0x0F79, 0x0F79, 1);
    VSBODY(pc, bb);
  }
  {                                          // chunk 50: no issue; drain 12->6
    short8 bb[6];
    READCH(50, bb, 0x0F79, 0x0F76, 0);
    VSBODY(4, bb);
  }
  {                                          // chunk 51: drain 6->0
    short8 bb[6];
    READCH(51, bb, 0x0F73, 0x0F70, 0);
    VSBODY(5, bb);
  }

  // ---- gather partials: T0 = sub0's 12 tiles, T1 = sub1's ----
  f32x4 T0[12], T1[12];
  #pragma unroll
  for (int t = 0; t < 6; t++){ T0[t] = accS[0][t]; T1[t] = accS[1][t]; }
  #pragma unroll
  for (int t = 0; t < 2; t++)
    #pragma unroll
    for (int i = 0; i < 3; i++){
      T0[6+3*t+i] = accV[0][i][t]; T1[6+3*t+i] = accV[1][i][t];
    }

  // ---- cross-wave K-reduction through reused ring (A=slots0-11, B=12-23) ----
  #define PUT12(base, T) { _Pragma("unroll") for (int j=0;j<12;j++) \
    *(f32x4*)(redf + ((base)+j)*320 + ln*20 + (quad<<2)) = T[j]; }
  #define ADD12(base, T) { _Pragma("unroll") for (int j=0;j<12;j++) \
    T[j] += *(const f32x4*)(redf + ((base)+j)*320 + ln*20 + (quad<<2)); }

  __syncthreads();                               // all waves drained own DMA (vmcnt 0)
  if (wv==1) PUT12(0, T0);  if (wv==2) PUT12(12, T1);
  __syncthreads();
  if (wv==0) ADD12(0, T0);  if (wv==3) ADD12(12, T1);
  __syncthreads();
  if (wv==2) PUT12(0, T0);  if (wv==1) PUT12(12, T1);
  __syncthreads();
  if (wv==0) ADD12(0, T0);  if (wv==3) ADD12(12, T1);
  __syncthreads();
  if (wv==3) PUT12(0, T0);  if (wv==0) PUT12(12, T1);
  __syncthreads();
  if (wv==0) ADD12(0, T0);  if (wv==3) ADD12(12, T1);
  // w0 now owns final sub0 tiles in T0; w3 owns final sub1 in T1.

  if (wv == 1 || wv == 2) return;
  const int s = (wv == 0) ? 0 : 1;
  f32x4* P = (wv == 0) ? T0 : T1;

  // ---- FC chain (owner wave, wave-private h buffer aliased on x1 region) ----
  f32x4 accF[4] = {z4,z4,z4,z4};
  {
    const float* fwp = few + (size_t)(ebase + s*16 + ln)*128;
    const short8* B = (const short8*)(wsb + FC1_OFF);
    #pragma unroll
    for (int c = 0; c < 4; c++){
      float4 fa  = *(const float4*)(fwp + c*32 + q8);
      float4 fbv = *(const float4*)(fwp + c*32 + q8 + 4);
      U8 a;
      a.u[0]=f2b2(fa.x,fa.y);   a.u[1]=f2b2(fa.z,fa.w);
      a.u[2]=f2b2(fbv.x,fbv.y); a.u[3]=f2b2(fbv.z,fbv.w);
      #pragma unroll
      for (int t = 0; t < 4; t++) accF[t] = mfma16(a.v, B[(c*4+t)*64 + lane], accF[t]);
    }
  }
  #pragma unroll
  for (int t = 0; t < 4; t++){
    float bb = fb1[(t<<4)+ln];
    #pragma unroll
    for (int r = 0; r < 4; r++)
      HB(wv, (quad<<2)+r, (t<<4)+ln) = f2b(silu_f(accF[t][r] + bb));
  }
  f32x4 acc2[4] = {z4,z4,z4,z4};
  {
    const short8* B = (const short8*)(wsb + FC2_OFF);
    #pragma unroll
    for (int c = 0; c < 2; c++){
      uint4 hq = *(const uint4*)&HB(wv, ln, c*32 + q8);
      U8 a; a.u[0]=hq.x; a.u[1]=hq.y; a.u[2]=hq.z; a.u[3]=hq.w;
      #pragma unroll
      for (int t = 0; t < 4; t++) acc2[t] = mfma16(a.v, B[(c*4+t)*64 + lane], acc2[t]);
    }
  }
  #pragma unroll
  for (int t = 0; t < 4; t++){
    float bb = fb2[(t<<4)+ln];
    #pragma unroll
    for (int r = 0; r < 4; r++)
      HB(wv, (quad<<2)+r, (t<<4)+ln) = f2b(silu_f(acc2[t][r] + bb));
  }
  f32x4 acc3[6] = {z4,z4,z4,z4,z4,z4};
  {
    const short8* B = (const short8*)(wsb + FC3_OFF);
    #pragma unroll
    for (int c = 0; c < 2; c++){
      uint4 hq = *(const uint4*)&HB(wv, ln, c*32 + q8);
      U8 a; a.u[0]=hq.x; a.u[1]=hq.y; a.u[2]=hq.z; a.u[3]=hq.w;
      #pragma unroll
      for (int t = 0; t < 6; t++) acc3[t] = mfma16(a.v, B[(c*6+t)*64 + lane], acc3[t]);
    }
  }

  // ---- epilogue (C-layout row = quad*4+r; 625*32 = 20000, no guards) ----
  #pragma unroll
  for (int r = 0; r < 4; r++){
    int eg = ebase + s*16 + (quad<<2) + r;
    float* op = out + (size_t)eg*160;
    #pragma unroll
    for (int t = 0; t < 4; t++)
      op[(t<<4)+ln] = silu_f(P[t][r]) * (acc3[t][r] + fb3[(t<<4)+ln]);
    #pragma unroll
    for (int tp = 0; tp < 2; tp++){
      int wc = (tp<<4) + ln;
      float f = sigm_f(P[4+tp][r]) * (acc3[4+tp][r] + fb3[64+wc]);
      op[64 + wc*3 + 0] = P[6+3*tp+0][r] * f;
      op[64 + wc*3 + 1] = P[6+3*tp+1][r] * f;
      op[64 + wc*3 + 2] = P[6+3*tp+2][r] * f;
    }
  }
}

extern "C" void kernel_launch(void* const* d_in, const int* in_sizes, int n_in,
                              void* d_out, int out_size, void* d_ws, size_t ws_size,
                              hipStream_t stream) {
  (void)in_sizes; (void)n_in; (void)out_size; (void)ws_size;
  unsigned short* wsb = (unsigned short*)d_ws;

  prep_weights<<<(WS_USH/8 + 255)/256, 256, 0, stream>>>(
      (const float*)d_in[3], (const float*)d_in[5],     // ss_s, ss_g
      (const float*)d_in[4], (const float*)d_in[6],     // vv_s, vv_g
      (const float*)d_in[7], (const float*)d_in[8],     // sv, vs
      (const float*)d_in[9], (const float*)d_in[11], (const float*)d_in[13],
      wsb);

  equiconv_main<<<E_TOT/32, 256, 0, stream>>>(
      (const float*)d_in[0], (const float*)d_in[1], (const float*)d_in[2],
      (const float*)d_in[10], (const float*)d_in[12], (const float*)d_in[14],
      (const unsigned short*)wsb, (float*)d_out);
}